// Round 5
// baseline (416.354 us; speedup 1.0000x reference)
//
#include <hip/hip_runtime.h>
#include <math.h>

#define BB 64
#define SS 2048
#define HH 512
#define AA 128
#define MM (BB*SS)
#define BM 128   // rows per score block

typedef __attribute__((ext_vector_type(8)))  short short8;
typedef __attribute__((ext_vector_type(16))) float f32x16;

__device__ inline unsigned short f2bf_rne(float f) {
    unsigned u = __float_as_uint(f);
    unsigned r = (u + 0x7fff + ((u >> 16) & 1)) >> 16;
    return (unsigned short)r;
}
__device__ inline float bf2f(unsigned short h) {
    return __uint_as_float(((unsigned)h) << 16);
}
__device__ inline float fast_tanh(float x) {
    float t = __expf(2.0f * x);
    return 1.0f - 2.0f * __builtin_amdgcn_rcpf(t + 1.0f);
}

// ---------------------------------------------------------------------------
// Kernel 0: W1 [512,128] fp32 -> hi/lo bf16 in MFMA B-fragment lane order.
// Bf layout: [it(16)*2+s(2)][hilo(2)][ntile(4)][lane(64)][j(8)] shorts, 256 KB.
// Element at (it,s,hilo,nt,lane,j) = split(W1[k][n]) with
//   n = nt*32 + (lane&31),  k = it*32 + s*16 + (lane>>5)*8 + j.
// ---------------------------------------------------------------------------
__global__ __launch_bounds__(256) void prep_w1frag(
    const float* __restrict__ W1, unsigned short* __restrict__ Bf)
{
    int idx = blockIdx.x * 256 + threadIdx.x;   // 65536 = 128n * 512k
    int n = idx >> 9, k = idx & 511;
    float v = W1[k * AA + n];
    unsigned short h  = f2bf_rne(v);
    unsigned short lo = (unsigned short)(__float_as_uint(v - bf2f(h)) >> 16);
    int it = k >> 5, kk = k & 31;
    int s  = kk >> 4, hf = (kk >> 3) & 1, j = kk & 7;
    int nt = n >> 5, lane = hf * 32 + (n & 31);
    size_t base = ((((size_t)(it * 2 + s) * 2 + 0) * 4 + nt) * 64 + lane) * 8 + j;
    size_t off  = (size_t)4 * 64 * 8;   // hilo stride = 2048 shorts (BUGFIX: was 4096)
    Bf[base]       = h;
    Bf[base + off] = lo;
}

// ---------------------------------------------------------------------------
// Kernel 1: scores = tanh(X@W1+b1)@W2+b2, split-bf16 MFMA (3 products).
// 256 thr = 4 waves; block tile 128m x 128n; wave tile 64m x 64n
// (mt=2 x nt=2 of 32x32x16 MFMA). A: direct-global, in-register hi/lo split.
// B: coalesced loads from pre-shuffled fragment buffer (L2/L1 resident).
// NO barriers in the K-loop; one barrier for the epilogue n-reduction.
// ---------------------------------------------------------------------------
__global__ __launch_bounds__(256) void score_mfma(
    const float* __restrict__ X, const unsigned short* __restrict__ Bf,
    const float* __restrict__ b1, const float* __restrict__ W2,
    const float* __restrict__ b2, float* __restrict__ scores)
{
    __shared__ float part[2][2][32][2];   // [wm][mt][row][wn], 1 KB

    const int tid  = threadIdx.x;
    const int wave = tid >> 6;
    const int lane = tid & 63;
    const int l31  = lane & 31;
    const int half = lane >> 5;
    const int wm   = wave >> 1;     // m-half of block
    const int wn   = wave & 1;      // n-half of block
    const int m0   = blockIdx.x * BM;

    const float* arow[2];
    #pragma unroll
    for (int mt = 0; mt < 2; mt++)
        arow[mt] = X + (size_t)(m0 + wm * 64 + mt * 32 + l31) * HH;

    f32x16 acc[2][2];
    #pragma unroll
    for (int mt = 0; mt < 2; mt++)
        #pragma unroll
        for (int nt = 0; nt < 2; nt++)
            #pragma unroll
            for (int r = 0; r < 16; r++) acc[mt][nt][r] = 0.f;

    float4 apre[2][2][2];   // [mt][s][jhalf]
    #pragma unroll
    for (int mt = 0; mt < 2; mt++)
        #pragma unroll
        for (int s = 0; s < 2; s++) {
            const float* p = arow[mt] + s * 16 + half * 8;
            apre[mt][s][0] = *(const float4*)p;
            apre[mt][s][1] = *(const float4*)(p + 4);
        }

    for (int it = 0; it < 16; it++) {
        // convert A fragments for this iter (frees apre)
        short8 ah[2][2], al[2][2];
        #pragma unroll
        for (int mt = 0; mt < 2; mt++)
            #pragma unroll
            for (int s = 0; s < 2; s++) {
                float fs[8];
                *(float4*)&fs[0] = apre[mt][s][0];
                *(float4*)&fs[4] = apre[mt][s][1];
                #pragma unroll
                for (int j = 0; j < 8; j++) {
                    unsigned short h = f2bf_rne(fs[j]);
                    ah[mt][s][j] = (short)h;
                    al[mt][s][j] = (short)(__float_as_uint(fs[j] - bf2f(h)) >> 16);
                }
            }
        // prefetch next-iter A
        if (it < 15) {
            #pragma unroll
            for (int mt = 0; mt < 2; mt++)
                #pragma unroll
                for (int s = 0; s < 2; s++) {
                    const float* p = arow[mt] + (it + 1) * 32 + s * 16 + half * 8;
                    apre[mt][s][0] = *(const float4*)p;
                    apre[mt][s][1] = *(const float4*)(p + 4);
                }
        }
        // MFMA: B fragments straight from pre-shuffled buffer
        #pragma unroll
        for (int s = 0; s < 2; s++) {
            const unsigned short* bsrc =
                Bf + ((size_t)(it * 2 + s) * 2) * (4 * 64 * 8) + (size_t)lane * 8;
            #pragma unroll
            for (int nt = 0; nt < 2; nt++) {
                const int ntg = wn * 2 + nt;
                short8 bh = *(const short8*)(bsrc + (size_t)ntg * (64 * 8));
                short8 bl = *(const short8*)(bsrc + (size_t)(4 + ntg) * (64 * 8));
                #pragma unroll
                for (int mt = 0; mt < 2; mt++) {
                    acc[mt][nt] = __builtin_amdgcn_mfma_f32_32x32x16_bf16(ah[mt][s], bh, acc[mt][nt], 0, 0, 0);
                    acc[mt][nt] = __builtin_amdgcn_mfma_f32_32x32x16_bf16(ah[mt][s], bl, acc[mt][nt], 0, 0, 0);
                    acc[mt][nt] = __builtin_amdgcn_mfma_f32_32x32x16_bf16(al[mt][s], bh, acc[mt][nt], 0, 0, 0);
                }
            }
        }
    }

    // ---- epilogue: tanh + dot(W2) over this wave's 64 n; cross-wave reduce
    #pragma unroll
    for (int mt = 0; mt < 2; mt++) {
        float p[16];
        #pragma unroll
        for (int r = 0; r < 16; r++) p[r] = 0.f;
        #pragma unroll
        for (int nt = 0; nt < 2; nt++) {
            int n = wn * 64 + nt * 32 + l31;
            float bias = b1[n];
            float w2   = W2[n];
            #pragma unroll
            for (int r = 0; r < 16; r++)
                p[r] += fast_tanh(acc[mt][nt][r] + bias) * w2;
        }
        #pragma unroll
        for (int off = 16; off > 0; off >>= 1)
            #pragma unroll
            for (int r = 0; r < 16; r++)
                p[r] += __shfl_xor(p[r], off);
        if (l31 == 0) {
            #pragma unroll
            for (int r = 0; r < 16; r++) {
                int row = (r & 3) + 8 * (r >> 2) + 4 * half;
                part[wm][mt][row][wn] = p[r];
            }
        }
    }
    __syncthreads();
    if (tid < 128) {
        int wmm = tid >> 6, mtt = (tid >> 5) & 1, row = tid & 31;
        scores[m0 + wmm * 64 + mtt * 32 + row] =
            part[wmm][mtt][row][0] + part[wmm][mtt][row][1] + b2[0];
    }
}

// ---------------------------------------------------------------------------
// Kernel 2: exact entmax-1.5 via bisection on sum(max(s-tau,0)^2) = 1.
// ---------------------------------------------------------------------------
__global__ __launch_bounds__(256) void entmax_bisect(
    const float* __restrict__ scores, float* __restrict__ weights)
{
    __shared__ float red[4];
    const int t = threadIdx.x, b = blockIdx.x;
    const int wv = t >> 6, ln = t & 63;
    const float* row = scores + (size_t)b * SS;

    float v[8];
    #pragma unroll
    for (int i = 0; i < 8; i++) v[i] = row[t + 256 * i];

    float mx = v[0];
    #pragma unroll
    for (int i = 1; i < 8; i++) mx = fmaxf(mx, v[i]);
    #pragma unroll
    for (int off = 32; off > 0; off >>= 1) mx = fmaxf(mx, __shfl_xor(mx, off));
    if (ln == 0) red[wv] = mx;
    __syncthreads();
    mx = fmaxf(fmaxf(red[0], red[1]), fmaxf(red[2], red[3]));

    #pragma unroll
    for (int i = 0; i < 8; i++) v[i] = (v[i] - mx) * 0.5f;

    float lo = -1.0f, hi = 0.0f;
    for (int it = 0; it < 32; it++) {
        float tm = 0.5f * (lo + hi);
        float s = 0.f;
        #pragma unroll
        for (int i = 0; i < 8; i++) {
            float d = fmaxf(v[i] - tm, 0.f);
            s = fmaf(d, d, s);
        }
        #pragma unroll
        for (int off = 32; off > 0; off >>= 1) s += __shfl_xor(s, off);
        __syncthreads();
        if (ln == 0) red[wv] = s;
        __syncthreads();
        s = red[0] + red[1] + red[2] + red[3];
        if (s >= 1.0f) lo = tm; else hi = tm;
    }
    float tau = 0.5f * (lo + hi);

    #pragma unroll
    for (int i = 0; i < 8; i++) {
        float d = fmaxf(v[i] - tau, 0.f);
        weights[(size_t)b * SS + t + 256 * i] = d * d;
    }
}

// ---------------------------------------------------------------------------
// Kernel 3: context[b,h] = sum_s X[b,s,h]*w[b,s], skipping w==0 rows.
// ---------------------------------------------------------------------------
__global__ __launch_bounds__(256) void context_kernel(
    const float* __restrict__ X, const float* __restrict__ weights,
    float* __restrict__ ctx)
{
    const int b = blockIdx.y;
    const int chunk = blockIdx.x;
    const int tid = threadIdx.x;
    const float* wrow  = weights + (size_t)b * SS + chunk * 64;
    const float* xbase = X + ((size_t)b * SS + (size_t)chunk * 64) * HH;
    float acc0 = 0.f, acc1 = 0.f;
    bool any = false;
    for (int s = 0; s < 64; s++) {
        float w = wrow[s];
        if (w != 0.f) {
            any = true;
            float2 x = *(const float2*)(xbase + (size_t)s * HH + 2 * tid);
            acc0 = fmaf(x.x, w, acc0);
            acc1 = fmaf(x.y, w, acc1);
        }
    }
    if (any) {
        atomicAdd(&ctx[b * HH + 2 * tid],     acc0);
        atomicAdd(&ctx[b * HH + 2 * tid + 1], acc1);
    }
}

// ---------------------------------------------------------------------------
extern "C" void kernel_launch(void* const* d_in, const int* in_sizes, int n_in,
                              void* d_out, int out_size, void* d_ws, size_t ws_size,
                              hipStream_t stream) {
    const float* X  = (const float*)d_in[0];   // [64,2048,512]
    const float* W1 = (const float*)d_in[1];   // [512,128]
    const float* b1 = (const float*)d_in[2];   // [128]
    const float* W2 = (const float*)d_in[3];   // [128,1]
    const float* b2 = (const float*)d_in[4];   // [1]

    float* out     = (float*)d_out;
    float* ctx     = out;                      // [64,512]
    float* weights = out + BB * HH;            // [64,2048]
    float* scores  = weights;                  // staged in weights region

    unsigned short* Bf = (unsigned short*)d_ws;   // 256 KB fragment buffer

    hipMemsetAsync(ctx, 0, (size_t)BB * HH * sizeof(float), stream);
    prep_w1frag<<<dim3(256), 256, 0, stream>>>(W1, Bf);
    score_mfma<<<dim3(MM / BM), 256, 0, stream>>>(X, Bf, b1, W2, b2, scores);
    entmax_bisect<<<dim3(BB), 256, 0, stream>>>(scores, weights);
    context_kernel<<<dim3(32, BB), 256, 0, stream>>>(X, weights, ctx);
}